// Round 2
// baseline (1372.894 us; speedup 1.0000x reference)
//
#include <hip/hip_runtime.h>

#define NTOK 16384
#define BATCH 4

// ---------------- workspace layout (floats) ----------------
// qkv   : (B*N, 768)  = 50331648   (q slot is overwritten by x after attn)
// bias  : (B*N, 64)   =  4194304
// kcvc  : (B,2,H,64,32) = 131072
// asum  : (B,64)      =      256
// total = 54657280 floats = 218.6 MB
#define OFF_QKV  0
#define OFF_BIAS 50331648
#define OFF_KCVC 54525952
#define OFF_ASUM 54657024

__global__ __launch_bounds__(256) void zero_f(float* __restrict__ p, int n) {
  int i = blockIdx.x * 256 + threadIdx.x;
  if (i < n) p[i] = 0.f;
}

// C[M,N] = A[M,K] @ B[K,N] (+ bias[N]); A row-stride lda. 128x128 tile, BK=16,
// 256 threads, 8x8 microtile, register prefetch of next staging tile.
template <int ADD_BIAS>
__global__ __launch_bounds__(256) void gemm128(const float* __restrict__ A,
                                               const float* __restrict__ B,
                                               const float* __restrict__ bias,
                                               float* __restrict__ C,
                                               int M, int N, int K, int lda) {
  __shared__ float As[16][132];
  __shared__ float Bs[16][132];
  const int tid = threadIdx.x;
  const int tx = tid & 15, ty = tid >> 4;
  const int bn = blockIdx.x * 128, bm = blockIdx.y * 128;

  float acc[8][8];
#pragma unroll
  for (int i = 0; i < 8; ++i)
#pragma unroll
    for (int j = 0; j < 8; ++j) acc[i][j] = 0.f;

  float4 pa[2], pb[2];
#pragma unroll
  for (int u = 0; u < 2; ++u) {
    int i = tid + u * 256;
    int row = i >> 2, k4 = (i & 3) << 2;
    pa[u] = *(const float4*)(A + (size_t)(bm + row) * lda + k4);
    int krow = i >> 5, nc4 = (i & 31) << 2;
    pb[u] = *(const float4*)(B + (size_t)krow * N + bn + nc4);
  }

  const int nkt = K >> 4;
  for (int kt = 0; kt < nkt; ++kt) {
    __syncthreads();
#pragma unroll
    for (int u = 0; u < 2; ++u) {
      int i = tid + u * 256;
      int row = i >> 2, k4 = (i & 3) << 2;
      As[k4 + 0][row] = pa[u].x;
      As[k4 + 1][row] = pa[u].y;
      As[k4 + 2][row] = pa[u].z;
      As[k4 + 3][row] = pa[u].w;
      int krow = i >> 5, nc4 = (i & 31) << 2;
      *(float4*)&Bs[krow][nc4] = pb[u];
    }
    __syncthreads();
    if (kt + 1 < nkt) {
      int k0 = (kt + 1) << 4;
#pragma unroll
      for (int u = 0; u < 2; ++u) {
        int i = tid + u * 256;
        int row = i >> 2, k4 = (i & 3) << 2;
        pa[u] = *(const float4*)(A + (size_t)(bm + row) * lda + k0 + k4);
        int krow = i >> 5, nc4 = (i & 31) << 2;
        pb[u] = *(const float4*)(B + (size_t)(k0 + krow) * N + bn + nc4);
      }
    }
#pragma unroll
    for (int k = 0; k < 16; ++k) {
      float a[8], b[8];
      *(float4*)(a) = *(const float4*)&As[k][ty * 8];
      *(float4*)(a + 4) = *(const float4*)&As[k][ty * 8 + 4];
      *(float4*)(b) = *(const float4*)&Bs[k][tx * 8];
      *(float4*)(b + 4) = *(const float4*)&Bs[k][tx * 8 + 4];
#pragma unroll
      for (int i = 0; i < 8; ++i)
#pragma unroll
        for (int j = 0; j < 8; ++j) acc[i][j] = fmaf(a[i], b[j], acc[i][j]);
    }
  }

  float4 b0 = {0, 0, 0, 0}, b1 = {0, 0, 0, 0};
  if (ADD_BIAS) {
    b0 = *(const float4*)(bias + bn + tx * 8);
    b1 = *(const float4*)(bias + bn + tx * 8 + 4);
  }
#pragma unroll
  for (int i = 0; i < 8; ++i) {
    int row = bm + ty * 8 + i;
    float* cp = C + (size_t)row * N + bn + tx * 8;
    float4 v0, v1;
    v0.x = acc[i][0] + b0.x; v0.y = acc[i][1] + b0.y;
    v0.z = acc[i][2] + b0.z; v0.w = acc[i][3] + b0.w;
    v1.x = acc[i][4] + b1.x; v1.y = acc[i][5] + b1.y;
    v1.z = acc[i][6] + b1.z; v1.w = acc[i][7] + b1.w;
    *(float4*)cp = v0;
    *(float4*)(cp + 4) = v1;
  }
}

// kcvc[b,p,h,k,d] += sum_n A[b,n,k] * qkv[b,n,256 + p*256 + h*32 + d]
// asum[b,k] += sum_n A[b,n,k]
// grid (64, B); chunk = 256 tokens; thread = (kg 0..7) x (cg 0..31), 8k x 16c'
__global__ __launch_bounds__(256) void pool_kernel(const float* __restrict__ A,
                                                   const float* __restrict__ qkv,
                                                   float* __restrict__ kcvc,
                                                   float* __restrict__ asum) {
  __shared__ float Al[4][64];
  __shared__ float KVl[4][512];
  const int tid = threadIdx.x;
  const int b = blockIdx.y;
  const int n0 = blockIdx.x * 256;
  const int kg = tid >> 5;
  const int cg = tid & 31;

  float acc[8][16];
#pragma unroll
  for (int i = 0; i < 8; ++i)
#pragma unroll
    for (int j = 0; j < 16; ++j) acc[i][j] = 0.f;
  float asl = 0.f;

  const int jrA = tid >> 6, kkA = tid & 63;
  float pa = A[((size_t)b * NTOK + n0 + jrA) * 64 + kkA];
  float4 pkv[2];
#pragma unroll
  for (int u = 0; u < 2; ++u) {
    int i = tid + u * 256;
    int jr = i >> 7, c4 = (i & 127) << 2;
    pkv[u] = *(const float4*)(qkv + ((size_t)b * NTOK + n0 + jr) * 768 + 256 + c4);
  }

  for (int j0 = 0; j0 < 256; j0 += 4) {
    __syncthreads();
    Al[jrA][kkA] = pa;
#pragma unroll
    for (int u = 0; u < 2; ++u) {
      int i = tid + u * 256;
      int jr = i >> 7, c4 = (i & 127) << 2;
      *(float4*)&KVl[jr][c4] = pkv[u];
    }
    __syncthreads();
    if (j0 + 4 < 256) {
      int nn = n0 + j0 + 4;
      pa = A[((size_t)b * NTOK + nn + jrA) * 64 + kkA];
#pragma unroll
      for (int u = 0; u < 2; ++u) {
        int i = tid + u * 256;
        int jr = i >> 7, c4 = (i & 127) << 2;
        pkv[u] = *(const float4*)(qkv + ((size_t)b * NTOK + nn + jr) * 768 + 256 + c4);
      }
    }
#pragma unroll
    for (int j = 0; j < 4; ++j) {
      float av[8], kv[16];
      *(float4*)(av) = *(const float4*)&Al[j][kg * 8];
      *(float4*)(av + 4) = *(const float4*)&Al[j][kg * 8 + 4];
#pragma unroll
      for (int u = 0; u < 4; ++u) *(float4*)(kv + 4 * u) = *(const float4*)&KVl[j][cg * 16 + 4 * u];
#pragma unroll
      for (int ii = 0; ii < 8; ++ii)
#pragma unroll
        for (int jj = 0; jj < 16; ++jj) acc[ii][jj] = fmaf(av[ii], kv[jj], acc[ii][jj]);
    }
    if (tid < 64) {
#pragma unroll
      for (int j = 0; j < 4; ++j) asl += Al[j][tid];
    }
  }

#pragma unroll
  for (int ii = 0; ii < 8; ++ii) {
    int k = kg * 8 + ii;
#pragma unroll
    for (int jj = 0; jj < 16; ++jj) {
      int c = cg * 16 + jj;
      int part = c >> 8, h = (c >> 5) & 7, d = c & 31;
      atomicAdd(&kcvc[((((size_t)b * 2 + part) * 8 + h) * 64 + k) * 32 + d], acc[ii][jj]);
    }
  }
  if (tid < 64) atomicAdd(&asum[b * 64 + tid], asl);
}

// kcvc /= (asum + eps); k-part also * 1/sqrt(32)
__global__ __launch_bounds__(256) void norm_kernel(float* __restrict__ kcvc,
                                                   const float* __restrict__ asum) {
  int i = blockIdx.x * 256 + threadIdx.x;  // 131072 total
  int k = (i >> 5) & 63;
  int p = (i >> 14) & 1;
  int b = i >> 15;
  float denom = asum[b * 64 + k] + 1e-8f;
  float s = p ? 1.0f : 0.17677669529663687f;  // 1/sqrt(32)
  kcvc[i] = kcvc[i] * s / denom;
}

// bias[b,n,l] = sum_j A[b,n,j] * cb[j,l]
__global__ __launch_bounds__(256) void bias_kernel(const float* __restrict__ A,
                                                   const float* __restrict__ cb,
                                                   float* __restrict__ bout) {
  size_t i = (size_t)blockIdx.x * 256 + threadIdx.x;  // 0..B*NTOK-1
  const float* ar = A + i * 64;
  float a[64];
#pragma unroll
  for (int u = 0; u < 16; ++u) *(float4*)(a + 4 * u) = *(const float4*)(ar + 4 * u);
  float o[64];
#pragma unroll
  for (int l = 0; l < 64; ++l) o[l] = 0.f;
#pragma unroll
  for (int j = 0; j < 64; ++j)
#pragma unroll
    for (int l = 0; l < 64; ++l) o[l] = fmaf(a[j], cb[j * 64 + l], o[l]);
  float* op = bout + i * 64;
#pragma unroll
  for (int u = 0; u < 16; ++u) *(float4*)(op + 4 * u) = *(float4*)(o + 4 * u);
}

// one thread per (token, head): 64 cluster scores, softmax, weighted vc sum.
// Writes x into the q slot of qkv (q already consumed into registers).
__global__ __launch_bounds__(256) void attn_kernel(float* __restrict__ qkv,
                                                   const float* __restrict__ kcvc,
                                                   const float* __restrict__ bbuf) {
  const int n = blockIdx.x * 256 + threadIdx.x;
  const int h = blockIdx.y, b = blockIdx.z;
  const size_t rown = (size_t)b * NTOK + n;

  float q[32];
#pragma unroll
  for (int u = 0; u < 8; ++u)
    *(float4*)(q + 4 * u) = *(const float4*)(qkv + rown * 768 + h * 32 + 4 * u);

  float sc[64];
#pragma unroll
  for (int u = 0; u < 16; ++u)
    *(float4*)(sc + 4 * u) = *(const float4*)(bbuf + rown * 64 + 4 * u);

  const float* kc = kcvc + (((size_t)b * 2 + 0) * 8 + h) * 2048;  // scale pre-folded
  const float* vc = kcvc + (((size_t)b * 2 + 1) * 8 + h) * 2048;

#pragma unroll
  for (int k = 0; k < 64; ++k) {
    float s = sc[k];
#pragma unroll
    for (int d = 0; d < 32; ++d) s = fmaf(q[d], kc[k * 32 + d], s);
    sc[k] = s;
  }

  float m = sc[0];
#pragma unroll
  for (int k = 1; k < 64; ++k) m = fmaxf(m, sc[k]);
  float l = 0.f;
#pragma unroll
  for (int k = 0; k < 64; ++k) {
    float e = __expf(sc[k] - m);
    sc[k] = e;
    l += e;
  }
  float rl = 1.f / l;

  float xo[32];
#pragma unroll
  for (int d = 0; d < 32; ++d) xo[d] = 0.f;
#pragma unroll
  for (int k = 0; k < 64; ++k) {
    float p = sc[k];
#pragma unroll
    for (int d = 0; d < 32; ++d) xo[d] = fmaf(p, vc[k * 32 + d], xo[d]);
  }

  float* xp = qkv + rown * 768 + h * 32;  // overwrite own q fragment
#pragma unroll
  for (int u = 0; u < 8; ++u) {
    float4 v;
    v.x = xo[4 * u + 0] * rl;
    v.y = xo[4 * u + 1] * rl;
    v.z = xo[4 * u + 2] * rl;
    v.w = xo[4 * u + 3] * rl;
    *(float4*)(xp + 4 * u) = v;
  }
}

extern "C" void kernel_launch(void* const* d_in, const int* in_sizes, int n_in,
                              void* d_out, int out_size, void* d_ws, size_t ws_size,
                              hipStream_t stream) {
  const float* voxel  = (const float*)d_in[0];  // (B,N,C)
  const float* A      = (const float*)d_in[1];  // (B,N,K)
  const float* w_qkv  = (const float*)d_in[2];  // (C,3C)
  const float* w_proj = (const float*)d_in[3];  // (C,C)
  const float* b_proj = (const float*)d_in[4];  // (C,)
  const float* cb     = (const float*)d_in[5];  // (K,K)
  float* out = (float*)d_out;

  float* ws    = (float*)d_ws;
  float* qkv   = ws + OFF_QKV;
  float* bbuf  = ws + OFF_BIAS;
  float* kcvc  = ws + OFF_KCVC;
  float* asum  = ws + OFF_ASUM;

  // zero accumulators (ws is poisoned 0xAA each launch); kcvc+asum contiguous
  zero_f<<<514, 256, 0, stream>>>(kcvc, 131072 + 256);

  // qkv = voxel @ w_qkv : (65536,256)@(256,768)
  gemm128<0><<<dim3(6, 512), 256, 0, stream>>>(voxel, w_qkv, nullptr, qkv,
                                               BATCH * NTOK, 768, 256, 256);

  // cluster-pooled K/V sums + cluster mass
  pool_kernel<<<dim3(64, BATCH), 256, 0, stream>>>(A, qkv, kcvc, asum);

  // bias = A @ cluster_bias
  bias_kernel<<<(BATCH * NTOK) / 256, 256, 0, stream>>>(A, cb, bbuf);

  // normalize pooled K/V (fold 1/denom and qk scale)
  norm_kernel<<<512, 256, 0, stream>>>(kcvc, asum);

  // attention -> x written into q slot of qkv (stride 768)
  attn_kernel<<<dim3(NTOK / 256, 8, BATCH), 256, 0, stream>>>(qkv, kcvc, bbuf);

  // out = x @ w_proj + b_proj : (65536,256)@(256,256), A row-stride 768
  gemm128<1><<<dim3(2, 512), 256, 0, stream>>>(qkv, w_proj, b_proj, out,
                                               BATCH * NTOK, 256, 256, 768);
}

// Round 3
// 922.695 us; speedup vs baseline: 1.4879x; 1.4879x over previous
//
#include <hip/hip_runtime.h>

#define NTOK 16384
#define BATCH 4

// ---------------- workspace layout (floats) ----------------
// qkv  : (B*N, 768) = 50331648   (q slot overwritten by x after attn)
// part : (B, nch, 512, 64)  = nch*131072   -- aliased with bbuf (part dead first)
// bbuf : (B*N, 64)  = 4194304
// kcvc : (B,2,H,64,32) = 131072
// asum : (B,64) = 256
#define OFF_QKV 0
#define OFF_PART 50331648

__global__ __launch_bounds__(256) void zero_f(float* __restrict__ p, int n) {
  int i = blockIdx.x * 256 + threadIdx.x;
  if (i < n) p[i] = 0.f;
}

// C[M,N] = A[M,K] @ B[K,N] (+ bias[N]); A row-stride lda. 128x128 tile, BK=16,
// 256 threads, 8x8 microtile, register prefetch of next staging tile.
template <int ADD_BIAS>
__global__ __launch_bounds__(256) void gemm128(const float* __restrict__ A,
                                               const float* __restrict__ B,
                                               const float* __restrict__ bias,
                                               float* __restrict__ C,
                                               int M, int N, int K, int lda) {
  __shared__ float As[16][132];
  __shared__ float Bs[16][132];
  const int tid = threadIdx.x;
  const int tx = tid & 15, ty = tid >> 4;
  const int bn = blockIdx.x * 128, bm = blockIdx.y * 128;

  float acc[8][8];
#pragma unroll
  for (int i = 0; i < 8; ++i)
#pragma unroll
    for (int j = 0; j < 8; ++j) acc[i][j] = 0.f;

  float4 pa[2], pb[2];
#pragma unroll
  for (int u = 0; u < 2; ++u) {
    int i = tid + u * 256;
    int row = i >> 2, k4 = (i & 3) << 2;
    pa[u] = *(const float4*)(A + (size_t)(bm + row) * lda + k4);
    int krow = i >> 5, nc4 = (i & 31) << 2;
    pb[u] = *(const float4*)(B + (size_t)krow * N + bn + nc4);
  }

  const int nkt = K >> 4;
  for (int kt = 0; kt < nkt; ++kt) {
    __syncthreads();
#pragma unroll
    for (int u = 0; u < 2; ++u) {
      int i = tid + u * 256;
      int row = i >> 2, k4 = (i & 3) << 2;
      As[k4 + 0][row] = pa[u].x;
      As[k4 + 1][row] = pa[u].y;
      As[k4 + 2][row] = pa[u].z;
      As[k4 + 3][row] = pa[u].w;
      int krow = i >> 5, nc4 = (i & 31) << 2;
      *(float4*)&Bs[krow][nc4] = pb[u];
    }
    __syncthreads();
    if (kt + 1 < nkt) {
      int k0 = (kt + 1) << 4;
#pragma unroll
      for (int u = 0; u < 2; ++u) {
        int i = tid + u * 256;
        int row = i >> 2, k4 = (i & 3) << 2;
        pa[u] = *(const float4*)(A + (size_t)(bm + row) * lda + k0 + k4);
        int krow = i >> 5, nc4 = (i & 31) << 2;
        pb[u] = *(const float4*)(B + (size_t)(k0 + krow) * N + bn + nc4);
      }
    }
#pragma unroll
    for (int k = 0; k < 16; ++k) {
      float a[8], b[8];
      *(float4*)(a) = *(const float4*)&As[k][ty * 8];
      *(float4*)(a + 4) = *(const float4*)&As[k][ty * 8 + 4];
      *(float4*)(b) = *(const float4*)&Bs[k][tx * 8];
      *(float4*)(b + 4) = *(const float4*)&Bs[k][tx * 8 + 4];
#pragma unroll
      for (int i = 0; i < 8; ++i)
#pragma unroll
        for (int j = 0; j < 8; ++j) acc[i][j] = fmaf(a[i], b[j], acc[i][j]);
    }
  }

  float4 b0 = {0, 0, 0, 0}, b1 = {0, 0, 0, 0};
  if (ADD_BIAS) {
    b0 = *(const float4*)(bias + bn + tx * 8);
    b1 = *(const float4*)(bias + bn + tx * 8 + 4);
  }
#pragma unroll
  for (int i = 0; i < 8; ++i) {
    int row = bm + ty * 8 + i;
    float* cp = C + (size_t)row * N + bn + tx * 8;
    float4 v0, v1;
    v0.x = acc[i][0] + b0.x; v0.y = acc[i][1] + b0.y;
    v0.z = acc[i][2] + b0.z; v0.w = acc[i][3] + b0.w;
    v1.x = acc[i][4] + b1.x; v1.y = acc[i][5] + b1.y;
    v1.z = acc[i][6] + b1.z; v1.w = acc[i][7] + b1.w;
    *(float4*)cp = v0;
    *(float4*)(cp + 4) = v1;
  }
}

// ---- pooling stage 1: barrier-free, atomic-free partial outer products ----
// wave = (b, c-tile of 32, n-chunk); lane = cluster k.
// per token j: v_a = A[row,lane] (coalesced vector load);
//              kv[0..31] = qkv[row, 256+c0 ..] (wave-uniform -> s_load);
//              acc[c] += kv[c] * v_a  (SGPR * VGPR fmac).
// part[b][ch][c][k] = acc  (coalesced stores, lane=k fastest).
__global__ __launch_bounds__(256) void pool1(const float* __restrict__ A,
                                             const float* __restrict__ qkv,
                                             float* __restrict__ part,
                                             int nch, int tokpc) {
  const int ch = blockIdx.x;
  const int b = blockIdx.z;
  const int wv = __builtin_amdgcn_readfirstlane(threadIdx.x >> 6);
  const int lane = threadIdx.x & 63;
  const int c0 = (blockIdx.y * 4 + wv) * 32;  // 0..480
  const size_t row0 = (size_t)b * NTOK + (size_t)ch * tokpc;

  const float* ap = A + row0 * 64 + lane;
  const float* kp = qkv + row0 * 768 + 256 + c0;  // wave-uniform

  float acc[32];
#pragma unroll
  for (int i = 0; i < 32; ++i) acc[i] = 0.f;

#pragma unroll 4
  for (int j = 0; j < tokpc; ++j) {
    float a = ap[(size_t)j * 64];
    float kv[32];
#pragma unroll
    for (int i = 0; i < 32; ++i) kv[i] = kp[(size_t)j * 768 + i];
#pragma unroll
    for (int i = 0; i < 32; ++i) acc[i] = fmaf(kv[i], a, acc[i]);
  }

  float* pp = part + (((size_t)b * nch + ch) * 512 + c0) * 64 + lane;
#pragma unroll
  for (int i = 0; i < 32; ++i) pp[(size_t)i * 64] = acc[i];
}

// ---- pooling stage 2: reduce chunks, fold 1/denom and qk scale ----
// cell id -> (b, c, k); kcvc[b][p][h][k][d], c = p*256 + h*32 + d
__global__ __launch_bounds__(256) void pool2(const float* __restrict__ part,
                                             const float* __restrict__ asum,
                                             float* __restrict__ kcvc, int nch) {
  int id = blockIdx.x * 256 + threadIdx.x;  // 0..131071
  int k = id & 63;
  int c = (id >> 6) & 511;
  int b = id >> 15;
  const float* pp = part + ((size_t)b * nch * 512 + c) * 64 + k;
  float s = 0.f;
#pragma unroll 4
  for (int ch = 0; ch < nch; ++ch) s += pp[(size_t)ch * 512 * 64];
  float denom = asum[b * 64 + k] + 1e-8f;
  int p = c >> 8, h = (c >> 5) & 7, d = c & 31;
  float scale = p ? 1.0f : 0.17677669529663687f;  // 1/sqrt(32) on K part
  kcvc[((((size_t)b * 2 + p) * 8 + h) * 64 + k) * 32 + d] = s * scale / denom;
}

// asum[b][k] = sum_n A[b,n,k];  grid (64, B), 256-token chunks
__global__ __launch_bounds__(256) void asum_kernel(const float* __restrict__ A,
                                                   float* __restrict__ asum) {
  __shared__ float red[4][64];
  const int ch = blockIdx.x, b = blockIdx.y;
  const int jq = threadIdx.x >> 6, k = threadIdx.x & 63;
  const size_t row0 = (size_t)b * NTOK + (size_t)ch * 256;
  const float* ap = A + (row0 + jq) * 64 + k;
  float s = 0.f;
#pragma unroll 4
  for (int j = 0; j < 64; ++j) s += ap[(size_t)j * 256];
  red[jq][k] = s;
  __syncthreads();
  if (threadIdx.x < 64) {
    float v = red[0][k] + red[1][k] + red[2][k] + red[3][k];
    atomicAdd(&asum[b * 64 + k], v);
  }
}

// bias[b,n,l] = sum_j A[b,n,j] * cb[j,l]
__global__ __launch_bounds__(256) void bias_kernel(const float* __restrict__ A,
                                                   const float* __restrict__ cb,
                                                   float* __restrict__ bout) {
  size_t i = (size_t)blockIdx.x * 256 + threadIdx.x;
  const float* ar = A + i * 64;
  float a[64];
#pragma unroll
  for (int u = 0; u < 16; ++u) *(float4*)(a + 4 * u) = *(const float4*)(ar + 4 * u);
  float o[64];
#pragma unroll
  for (int l = 0; l < 64; ++l) o[l] = 0.f;
#pragma unroll
  for (int j = 0; j < 64; ++j)
#pragma unroll
    for (int l = 0; l < 64; ++l) o[l] = fmaf(a[j], cb[j * 64 + l], o[l]);
  float* op = bout + i * 64;
#pragma unroll
  for (int u = 0; u < 16; ++u) *(float4*)(op + 4 * u) = *(float4*)(o + 4 * u);
}

// one thread per (token, head); writes x into q slot of qkv
__global__ __launch_bounds__(256) void attn_kernel(float* __restrict__ qkv,
                                                   const float* __restrict__ kcvc,
                                                   const float* __restrict__ bbuf) {
  const int n = blockIdx.x * 256 + threadIdx.x;
  const int h = blockIdx.y, b = blockIdx.z;
  const size_t rown = (size_t)b * NTOK + n;

  float q[32];
#pragma unroll
  for (int u = 0; u < 8; ++u)
    *(float4*)(q + 4 * u) = *(const float4*)(qkv + rown * 768 + h * 32 + 4 * u);

  float sc[64];
#pragma unroll
  for (int u = 0; u < 16; ++u)
    *(float4*)(sc + 4 * u) = *(const float4*)(bbuf + rown * 64 + 4 * u);

  const float* kc = kcvc + (((size_t)b * 2 + 0) * 8 + h) * 2048;
  const float* vc = kcvc + (((size_t)b * 2 + 1) * 8 + h) * 2048;

#pragma unroll
  for (int k = 0; k < 64; ++k) {
    float s = sc[k];
#pragma unroll
    for (int d = 0; d < 32; ++d) s = fmaf(q[d], kc[k * 32 + d], s);
    sc[k] = s;
  }

  float m = sc[0];
#pragma unroll
  for (int k = 1; k < 64; ++k) m = fmaxf(m, sc[k]);
  float l = 0.f;
#pragma unroll
  for (int k = 0; k < 64; ++k) {
    float e = __expf(sc[k] - m);
    sc[k] = e;
    l += e;
  }
  float rl = 1.f / l;

  float xo[32];
#pragma unroll
  for (int d = 0; d < 32; ++d) xo[d] = 0.f;
#pragma unroll
  for (int k = 0; k < 64; ++k) {
    float p = sc[k];
#pragma unroll
    for (int d = 0; d < 32; ++d) xo[d] = fmaf(p, vc[k * 32 + d], xo[d]);
  }

  float* xp = qkv + rown * 768 + h * 32;
#pragma unroll
  for (int u = 0; u < 8; ++u) {
    float4 v;
    v.x = xo[4 * u + 0] * rl;
    v.y = xo[4 * u + 1] * rl;
    v.z = xo[4 * u + 2] * rl;
    v.w = xo[4 * u + 3] * rl;
    *(float4*)(xp + 4 * u) = v;
  }
}

extern "C" void kernel_launch(void* const* d_in, const int* in_sizes, int n_in,
                              void* d_out, int out_size, void* d_ws, size_t ws_size,
                              hipStream_t stream) {
  const float* voxel  = (const float*)d_in[0];
  const float* A      = (const float*)d_in[1];
  const float* w_qkv  = (const float*)d_in[2];
  const float* w_proj = (const float*)d_in[3];
  const float* b_proj = (const float*)d_in[4];
  const float* cb     = (const float*)d_in[5];
  float* out = (float*)d_out;
  (void)in_sizes; (void)n_in; (void)out_size;

  // nch=64 needs 235.4 MB; fall back to nch=32 (218.6 MB, proven fit).
  // ws_size is constant across calls -> branch is graph-capture safe.
  const size_t big_fl = 50331648ull + 8388608ull + 131072ull + 256ull;
  const int nch = (ws_size >= big_fl * 4) ? 64 : 32;
  const int tokpc = NTOK / nch;
  const size_t part_fl = (size_t)nch * 131072ull;
  const size_t region = part_fl > 4194304ull ? part_fl : 4194304ull;

  float* ws   = (float*)d_ws;
  float* qkv  = ws + OFF_QKV;
  float* part = ws + OFF_PART;
  float* bbuf = ws + OFF_PART;              // aliased: part dead before bias
  float* kcvc = ws + OFF_PART + region;
  float* asum = kcvc + 131072;

  zero_f<<<1, 256, 0, stream>>>(asum, 256);

  // qkv = voxel @ w_qkv : (65536,256)@(256,768)
  gemm128<0><<<dim3(6, 512), 256, 0, stream>>>(voxel, w_qkv, nullptr, qkv,
                                               BATCH * NTOK, 768, 256, 256);

  asum_kernel<<<dim3(64, BATCH), 256, 0, stream>>>(A, asum);

  pool1<<<dim3(nch, 4, BATCH), 256, 0, stream>>>(A, qkv, part, nch, tokpc);
  pool2<<<512, 256, 0, stream>>>(part, asum, kcvc, nch);

  // bias = A @ cluster_bias (overwrites part region)
  bias_kernel<<<(BATCH * NTOK) / 256, 256, 0, stream>>>(A, cb, bbuf);

  // attention -> x written into q slot of qkv (stride 768)
  attn_kernel<<<dim3(NTOK / 256, 8, BATCH), 256, 0, stream>>>(qkv, kcvc, bbuf);

  // out = x @ w_proj + b_proj, A row-stride 768
  gemm128<1><<<dim3(2, 512), 256, 0, stream>>>(qkv, w_proj, b_proj, out,
                                               BATCH * NTOK, 256, 256, 768);
}

// Round 4
// 613.838 us; speedup vs baseline: 2.2366x; 1.5032x over previous
//
#include <hip/hip_runtime.h>

#define NTOK 16384
#define BATCH 4

typedef __attribute__((ext_vector_type(8))) short bf16x8;
typedef __attribute__((ext_vector_type(8))) unsigned short ushort8;
typedef __attribute__((ext_vector_type(4))) float f32x4;

__device__ __forceinline__ unsigned short f2bf(float f) {
  union { float f; unsigned int u; } c; c.f = f;
  unsigned int r = c.u + 0x7fff + ((c.u >> 16) & 1);  // RTN-even
  return (unsigned short)(r >> 16);
}

__global__ __launch_bounds__(256) void zero_f(float* __restrict__ p, int n) {
  int i = blockIdx.x * 256 + threadIdx.x;
  if (i < n) p[i] = 0.f;
}

// transpose+convert weights: wqkvT[n][k]=bf16(w_qkv[k][n]); wprojT[n][k]=bf16(w_proj[k][n])
__global__ __launch_bounds__(256) void convw(const float* __restrict__ w_qkv,
                                             const float* __restrict__ w_proj,
                                             unsigned short* __restrict__ wqT,
                                             unsigned short* __restrict__ wpT) {
  int n = blockIdx.x, k = threadIdx.x;
  if (n < 768) wqT[n * 256 + k] = f2bf(w_qkv[(size_t)k * 768 + n]);
  else wpT[(n - 768) * 256 + k] = f2bf(w_proj[(size_t)k * 256 + (n - 768)]);
}

// C[M,N] = A[M,K] @ BT[N,K]^T (+bias). MFMA bf16. Tile 128x128, BK=64, 4 waves.
// A_FP32: A is fp32 (converted to bf16 during staging); else A is bf16 (ushort).
template <int A_FP32, int ADD_BIAS>
__global__ __launch_bounds__(256) void gemm_mfma(const void* __restrict__ Av,
                                                 const unsigned short* __restrict__ BT,
                                                 const float* __restrict__ bias,
                                                 float* __restrict__ C,
                                                 int N, int K, int lda) {
  __shared__ unsigned short As[128][72];  // 144 B rows: b128-aligned, 2-way banks
  __shared__ unsigned short Bs[128][72];
  const int tid = threadIdx.x;
  const int bn = blockIdx.x * 128, bm = blockIdx.y * 128;
  const int lane = tid & 63;
  const int wv = tid >> 6;
  const int wm = wv & 1, wn = wv >> 1;
  const int m16 = lane & 15, quad = lane >> 4;

  const float* Af = (const float*)Av;
  const unsigned short* Ab = (const unsigned short*)Av;

  const int srow = tid >> 1;
  const int scol = (tid & 1) * 32;

  f32x4 acc[4][4];
#pragma unroll
  for (int r = 0; r < 4; ++r)
#pragma unroll
    for (int c = 0; c < 4; ++c) acc[r][c] = (f32x4){0.f, 0.f, 0.f, 0.f};

  float4 pa[8];
  ushort8 pab[4], pb[4];

  auto loadA = [&](int k0) {
    if (A_FP32) {
      const float* g = Af + (size_t)(bm + srow) * lda + k0 + scol;
#pragma unroll
      for (int i = 0; i < 8; ++i) pa[i] = *(const float4*)(g + 4 * i);
    } else {
      const unsigned short* g = Ab + (size_t)(bm + srow) * lda + k0 + scol;
#pragma unroll
      for (int i = 0; i < 4; ++i) pab[i] = *(const ushort8*)(g + 8 * i);
    }
  };
  auto loadB = [&](int k0) {
    const unsigned short* g = BT + (size_t)(bn + srow) * K + k0 + scol;
#pragma unroll
    for (int i = 0; i < 4; ++i) pb[i] = *(const ushort8*)(g + 8 * i);
  };

  loadA(0);
  loadB(0);

  const int nkt = K >> 6;
  for (int kt = 0; kt < nkt; ++kt) {
    __syncthreads();
    if (A_FP32) {
      unsigned short h[32];
#pragma unroll
      for (int i = 0; i < 8; ++i) {
        h[4 * i + 0] = f2bf(pa[i].x);
        h[4 * i + 1] = f2bf(pa[i].y);
        h[4 * i + 2] = f2bf(pa[i].z);
        h[4 * i + 3] = f2bf(pa[i].w);
      }
#pragma unroll
      for (int i = 0; i < 4; ++i) *(ushort8*)&As[srow][scol + 8 * i] = *(ushort8*)&h[8 * i];
    } else {
#pragma unroll
      for (int i = 0; i < 4; ++i) *(ushort8*)&As[srow][scol + 8 * i] = pab[i];
    }
#pragma unroll
    for (int i = 0; i < 4; ++i) *(ushort8*)&Bs[srow][scol + 8 * i] = pb[i];
    __syncthreads();
    if (kt + 1 < nkt) {
      loadA((kt + 1) << 6);
      loadB((kt + 1) << 6);
    }
#pragma unroll
    for (int ks = 0; ks < 64; ks += 32) {
      bf16x8 af[4], bf[4];
#pragma unroll
      for (int r = 0; r < 4; ++r)
        af[r] = *(const bf16x8*)&As[wm * 64 + r * 16 + m16][ks + quad * 8];
#pragma unroll
      for (int c = 0; c < 4; ++c)
        bf[c] = *(const bf16x8*)&Bs[wn * 64 + c * 16 + m16][ks + quad * 8];
#pragma unroll
      for (int r = 0; r < 4; ++r)
#pragma unroll
        for (int c = 0; c < 4; ++c)
          acc[r][c] = __builtin_amdgcn_mfma_f32_16x16x32_bf16(af[r], bf[c], acc[r][c], 0, 0, 0);
    }
  }

#pragma unroll
  for (int c = 0; c < 4; ++c) {
    int col = bn + wn * 64 + c * 16 + m16;
    float bv = ADD_BIAS ? bias[col] : 0.f;
#pragma unroll
    for (int r = 0; r < 4; ++r) {
      int row0 = bm + wm * 64 + r * 16 + quad * 4;
#pragma unroll
      for (int i = 0; i < 4; ++i)
        C[(size_t)(row0 + i) * N + col] = acc[r][c][i] + bv;
    }
  }
}

// ---- pooling stage 1: barrier-free, atomic-free partial outer products ----
__global__ __launch_bounds__(256) void pool1(const float* __restrict__ A,
                                             const float* __restrict__ qkv,
                                             float* __restrict__ part,
                                             int nch, int tokpc) {
  const int ch = blockIdx.x;
  const int b = blockIdx.z;
  const int wv = __builtin_amdgcn_readfirstlane(threadIdx.x >> 6);
  const int lane = threadIdx.x & 63;
  const int c0 = (blockIdx.y * 4 + wv) * 32;
  const size_t row0 = (size_t)b * NTOK + (size_t)ch * tokpc;

  const float* ap = A + row0 * 64 + lane;
  const float* kp = qkv + row0 * 768 + 256 + c0;

  float acc[32];
#pragma unroll
  for (int i = 0; i < 32; ++i) acc[i] = 0.f;

#pragma unroll 4
  for (int j = 0; j < tokpc; ++j) {
    float a = ap[(size_t)j * 64];
    float kv[32];
#pragma unroll
    for (int i = 0; i < 32; ++i) kv[i] = kp[(size_t)j * 768 + i];
#pragma unroll
    for (int i = 0; i < 32; ++i) acc[i] = fmaf(kv[i], a, acc[i]);
  }

  float* pp = part + (((size_t)b * nch + ch) * 512 + c0) * 64 + lane;
#pragma unroll
  for (int i = 0; i < 32; ++i) pp[(size_t)i * 64] = acc[i];
}

// ---- pooling stage 2: reduce chunks, fold 1/denom and qk scale ----
__global__ __launch_bounds__(256) void pool2(const float* __restrict__ part,
                                             const float* __restrict__ asum,
                                             float* __restrict__ kcvc, int nch) {
  int id = blockIdx.x * 256 + threadIdx.x;
  int k = id & 63;
  int c = (id >> 6) & 511;
  int b = id >> 15;
  const float* pp = part + ((size_t)b * nch * 512 + c) * 64 + k;
  float s = 0.f;
#pragma unroll 4
  for (int ch = 0; ch < nch; ++ch) s += pp[(size_t)ch * 512 * 64];
  float denom = asum[b * 64 + k] + 1e-8f;
  int p = c >> 8, h = (c >> 5) & 7, d = c & 31;
  float scale = p ? 1.0f : 0.17677669529663687f;
  kcvc[((((size_t)b * 2 + p) * 8 + h) * 64 + k) * 32 + d] = s * scale / denom;
}

__global__ __launch_bounds__(256) void asum_kernel(const float* __restrict__ A,
                                                   float* __restrict__ asum) {
  __shared__ float red[4][64];
  const int ch = blockIdx.x, b = blockIdx.y;
  const int jq = threadIdx.x >> 6, k = threadIdx.x & 63;
  const size_t row0 = (size_t)b * NTOK + (size_t)ch * 256;
  const float* ap = A + (row0 + jq) * 64 + k;
  float s = 0.f;
#pragma unroll 4
  for (int j = 0; j < 64; ++j) s += ap[(size_t)j * 256];
  red[jq][k] = s;
  __syncthreads();
  if (threadIdx.x < 64) {
    float v = red[0][k] + red[1][k] + red[2][k] + red[3][k];
    atomicAdd(&asum[b * 64 + k], v);
  }
}

__global__ __launch_bounds__(256) void bias_kernel(const float* __restrict__ A,
                                                   const float* __restrict__ cb,
                                                   float* __restrict__ bout) {
  size_t i = (size_t)blockIdx.x * 256 + threadIdx.x;
  const float* ar = A + i * 64;
  float a[64];
#pragma unroll
  for (int u = 0; u < 16; ++u) *(float4*)(a + 4 * u) = *(const float4*)(ar + 4 * u);
  float o[64];
#pragma unroll
  for (int l = 0; l < 64; ++l) o[l] = 0.f;
#pragma unroll
  for (int j = 0; j < 64; ++j)
#pragma unroll
    for (int l = 0; l < 64; ++l) o[l] = fmaf(a[j], cb[j * 64 + l], o[l]);
  float* op = bout + i * 64;
#pragma unroll
  for (int u = 0; u < 16; ++u) *(float4*)(op + 4 * u) = *(float4*)(o + 4 * u);
}

// one thread per (token, head); writes x (bf16) into the K-slot of qkv
__global__ __launch_bounds__(256) void attn_kernel(float* __restrict__ qkv,
                                                   const float* __restrict__ kcvc,
                                                   const float* __restrict__ bbuf) {
  const int n = blockIdx.x * 256 + threadIdx.x;
  const int h = blockIdx.y, b = blockIdx.z;
  const size_t rown = (size_t)b * NTOK + n;

  float q[32];
#pragma unroll
  for (int u = 0; u < 8; ++u)
    *(float4*)(q + 4 * u) = *(const float4*)(qkv + rown * 768 + h * 32 + 4 * u);

  float sc[64];
#pragma unroll
  for (int u = 0; u < 16; ++u)
    *(float4*)(sc + 4 * u) = *(const float4*)(bbuf + rown * 64 + 4 * u);

  const float* kc = kcvc + (((size_t)b * 2 + 0) * 8 + h) * 2048;
  const float* vc = kcvc + (((size_t)b * 2 + 1) * 8 + h) * 2048;

#pragma unroll
  for (int k = 0; k < 64; ++k) {
    float s = sc[k];
#pragma unroll
    for (int d = 0; d < 32; ++d) s = fmaf(q[d], kc[k * 32 + d], s);
    sc[k] = s;
  }

  float m = sc[0];
#pragma unroll
  for (int k = 1; k < 64; ++k) m = fmaxf(m, sc[k]);
  float l = 0.f;
#pragma unroll
  for (int k = 0; k < 64; ++k) {
    float e = __expf(sc[k] - m);
    sc[k] = e;
    l += e;
  }
  float rl = 1.f / l;

  float xo[32];
#pragma unroll
  for (int d = 0; d < 32; ++d) xo[d] = 0.f;
#pragma unroll
  for (int k = 0; k < 64; ++k) {
    float p = sc[k];
#pragma unroll
    for (int d = 0; d < 32; ++d) xo[d] = fmaf(p, vc[k * 32 + d], xo[d]);
  }

  unsigned short xh[32];
#pragma unroll
  for (int d = 0; d < 32; ++d) xh[d] = f2bf(xo[d] * rl);
  unsigned short* xp = (unsigned short*)(qkv + rown * 768 + 256) + h * 32;
#pragma unroll
  for (int i = 0; i < 4; ++i) *(ushort8*)(xp + 8 * i) = *(ushort8*)&xh[8 * i];
}

extern "C" void kernel_launch(void* const* d_in, const int* in_sizes, int n_in,
                              void* d_out, int out_size, void* d_ws, size_t ws_size,
                              hipStream_t stream) {
  const float* voxel  = (const float*)d_in[0];
  const float* A      = (const float*)d_in[1];
  const float* w_qkv  = (const float*)d_in[2];
  const float* w_proj = (const float*)d_in[3];
  const float* b_proj = (const float*)d_in[4];
  const float* cb     = (const float*)d_in[5];
  float* out = (float*)d_out;
  (void)in_sizes; (void)n_in; (void)out_size;

  // layout: qkv | region(part/bbuf aliased) | kcvc | asum | wqT | wpT
  const size_t FL_QKV = 50331648ull;
  const size_t big_fl = FL_QKV + 8388608ull + 131072ull + 256ull + 98304ull + 32768ull;
  const int nch = (ws_size >= big_fl * 4) ? 64 : 32;
  const int tokpc = NTOK / nch;
  const size_t region_fl = (size_t)nch * 131072ull;  // nch=32 -> 4194304 == bbuf size

  float* ws   = (float*)d_ws;
  float* qkv  = ws;
  float* part = ws + FL_QKV;
  float* bbuf = part;  // aliased: part dead before bias
  float* kcvc = part + region_fl;
  float* asum = kcvc + 131072;
  unsigned short* wqT = (unsigned short*)(asum + 256);
  unsigned short* wpT = wqT + 196608;

  zero_f<<<1, 256, 0, stream>>>(asum, 256);
  convw<<<1024, 256, 0, stream>>>(w_qkv, w_proj, wqT, wpT);

  // qkv = voxel @ w_qkv : MFMA bf16, A fp32 converted in staging
  gemm_mfma<1, 0><<<dim3(6, 512), 256, 0, stream>>>(voxel, wqT, nullptr, qkv,
                                                    768, 256, 256);

  asum_kernel<<<dim3(64, BATCH), 256, 0, stream>>>(A, asum);
  pool1<<<dim3(nch, 4, BATCH), 256, 0, stream>>>(A, qkv, part, nch, tokpc);
  pool2<<<512, 256, 0, stream>>>(part, asum, kcvc, nch);

  bias_kernel<<<(BATCH * NTOK) / 256, 256, 0, stream>>>(A, cb, bbuf);

  attn_kernel<<<dim3(NTOK / 256, 8, BATCH), 256, 0, stream>>>(qkv, kcvc, bbuf);

  // out = x @ w_proj + b_proj : A = bf16 x in K-slot of qkv (lda 1536 elems)
  const unsigned short* xb = (const unsigned short*)qkv + 512;
  gemm_mfma<0, 1><<<dim3(2, 512), 256, 0, stream>>>(xb, wpT, b_proj, out,
                                                    256, 256, 1536);
}

// Round 5
// 430.161 us; speedup vs baseline: 3.1916x; 1.4270x over previous
//
#include <hip/hip_runtime.h>

#define NTOK 16384
#define BATCH 4

typedef __attribute__((ext_vector_type(8))) short bf16x8;
typedef __attribute__((ext_vector_type(8))) unsigned short ushort8;
typedef __attribute__((ext_vector_type(4))) float f32x4;

__device__ __forceinline__ unsigned short f2bf(float f) {
  union { float f; unsigned int u; } c; c.f = f;
  unsigned int r = c.u + 0x7fff + ((c.u >> 16) & 1);  // RTN-even
  return (unsigned short)(r >> 16);
}
__device__ __forceinline__ float bf2f(unsigned short h) {
  union { unsigned int u; float f; } c; c.u = ((unsigned int)h) << 16;
  return c.f;
}

__global__ __launch_bounds__(256) void zero_f(float* __restrict__ p, int n) {
  int i = blockIdx.x * 256 + threadIdx.x;
  if (i < n) p[i] = 0.f;
}

// transpose+convert weights
__global__ __launch_bounds__(256) void convw(const float* __restrict__ w_qkv,
                                             const float* __restrict__ w_proj,
                                             unsigned short* __restrict__ wqT,
                                             unsigned short* __restrict__ wpT) {
  int n = blockIdx.x, k = threadIdx.x;
  if (n < 768) wqT[n * 256 + k] = f2bf(w_qkv[(size_t)k * 768 + n]);
  else wpT[(n - 768) * 256 + k] = f2bf(w_proj[(size_t)k * 256 + (n - 768)]);
}

// C[M,N] = A[M,K] @ BT[N,K]^T (+bias). MFMA bf16. Tile 128x128, BK=64, 4 waves.
// A_FP32: A fp32 (cvt in staging) else bf16. C_BF16: store bf16 else fp32.
template <int A_FP32, int ADD_BIAS, int C_BF16>
__global__ __launch_bounds__(256) void gemm_mfma(const void* __restrict__ Av,
                                                 const unsigned short* __restrict__ BT,
                                                 const float* __restrict__ bias,
                                                 void* __restrict__ Cv,
                                                 int N, int K, int lda) {
  __shared__ unsigned short As[128][72];
  __shared__ unsigned short Bs[128][72];
  const int tid = threadIdx.x;
  const int bn = blockIdx.x * 128, bm = blockIdx.y * 128;
  const int lane = tid & 63;
  const int wv = tid >> 6;
  const int wm = wv & 1, wn = wv >> 1;
  const int m16 = lane & 15, quad = lane >> 4;

  const float* Af = (const float*)Av;
  const unsigned short* Ab = (const unsigned short*)Av;

  const int srow = tid >> 1;
  const int scol = (tid & 1) * 32;

  f32x4 acc[4][4];
#pragma unroll
  for (int r = 0; r < 4; ++r)
#pragma unroll
    for (int c = 0; c < 4; ++c) acc[r][c] = (f32x4){0.f, 0.f, 0.f, 0.f};

  float4 pa[8];
  ushort8 pab[4], pb[4];

  auto loadA = [&](int k0) {
    if (A_FP32) {
      const float* g = Af + (size_t)(bm + srow) * lda + k0 + scol;
#pragma unroll
      for (int i = 0; i < 8; ++i) pa[i] = *(const float4*)(g + 4 * i);
    } else {
      const unsigned short* g = Ab + (size_t)(bm + srow) * lda + k0 + scol;
#pragma unroll
      for (int i = 0; i < 4; ++i) pab[i] = *(const ushort8*)(g + 8 * i);
    }
  };
  auto loadB = [&](int k0) {
    const unsigned short* g = BT + (size_t)(bn + srow) * K + k0 + scol;
#pragma unroll
    for (int i = 0; i < 4; ++i) pb[i] = *(const ushort8*)(g + 8 * i);
  };

  loadA(0);
  loadB(0);

  const int nkt = K >> 6;
  for (int kt = 0; kt < nkt; ++kt) {
    __syncthreads();
    if (A_FP32) {
      unsigned short h[32];
#pragma unroll
      for (int i = 0; i < 8; ++i) {
        h[4 * i + 0] = f2bf(pa[i].x);
        h[4 * i + 1] = f2bf(pa[i].y);
        h[4 * i + 2] = f2bf(pa[i].z);
        h[4 * i + 3] = f2bf(pa[i].w);
      }
#pragma unroll
      for (int i = 0; i < 4; ++i) *(ushort8*)&As[srow][scol + 8 * i] = *(ushort8*)&h[8 * i];
    } else {
#pragma unroll
      for (int i = 0; i < 4; ++i) *(ushort8*)&As[srow][scol + 8 * i] = pab[i];
    }
#pragma unroll
    for (int i = 0; i < 4; ++i) *(ushort8*)&Bs[srow][scol + 8 * i] = pb[i];
    __syncthreads();
    if (kt + 1 < nkt) {
      loadA((kt + 1) << 6);
      loadB((kt + 1) << 6);
    }
#pragma unroll
    for (int ks = 0; ks < 64; ks += 32) {
      bf16x8 af[4], bf[4];
#pragma unroll
      for (int r = 0; r < 4; ++r)
        af[r] = *(const bf16x8*)&As[wm * 64 + r * 16 + m16][ks + quad * 8];
#pragma unroll
      for (int c = 0; c < 4; ++c)
        bf[c] = *(const bf16x8*)&Bs[wn * 64 + c * 16 + m16][ks + quad * 8];
#pragma unroll
      for (int r = 0; r < 4; ++r)
#pragma unroll
        for (int c = 0; c < 4; ++c)
          acc[r][c] = __builtin_amdgcn_mfma_f32_16x16x32_bf16(af[r], bf[c], acc[r][c], 0, 0, 0);
    }
  }

#pragma unroll
  for (int c = 0; c < 4; ++c) {
    int col = bn + wn * 64 + c * 16 + m16;
    float bv = ADD_BIAS ? bias[col] : 0.f;
#pragma unroll
    for (int r = 0; r < 4; ++r) {
      int row0 = bm + wm * 64 + r * 16 + quad * 4;
#pragma unroll
      for (int i = 0; i < 4; ++i) {
        if (C_BF16)
          ((unsigned short*)Cv)[(size_t)(row0 + i) * N + col] = f2bf(acc[r][c][i] + bv);
        else
          ((float*)Cv)[(size_t)(row0 + i) * N + col] = acc[r][c][i] + bv;
      }
    }
  }
}

// ---- pooling via MFMA: part[b][tch][cl 64][ch 512] over 256-token chunks ----
// grid (64, 4, B); block 256 = 4 waves; wave handles all 64 cl x 32 ch.
__global__ __launch_bounds__(256) void pool_mfma(const float* __restrict__ A,
                                                 const unsigned short* __restrict__ qkv,
                                                 float* __restrict__ part) {
  __shared__ unsigned short At[64][40];    // 80 B rows: 16B-aligned
  __shared__ unsigned short KVt[128][40];
  const int tid = threadIdx.x;
  const int tch = blockIdx.x, cblk = blockIdx.y, b = blockIdx.z;
  const int w = tid >> 6, lane = tid & 63;
  const int m16 = lane & 15, quad = lane >> 4;
  const size_t row0 = (size_t)b * NTOK + (size_t)tch * 256;
  const int cb0 = cblk * 128;

  f32x4 acc[4][2];
#pragma unroll
  for (int r = 0; r < 4; ++r)
#pragma unroll
    for (int c = 0; c < 2; ++c) acc[r][c] = (f32x4){0.f, 0.f, 0.f, 0.f};

  ushort8 pkv[2];
  float4 pav[2];
  auto loadG = [&](int t0) {
#pragma unroll
    for (int u = 0; u < 2; ++u) {
      int idx = tid + u * 256;
      int tok = idx & 31, g = idx >> 5;  // g: 0..15
      pkv[u] = *(const ushort8*)(qkv + (row0 + t0 + tok) * 768 + 256 + cb0 + g * 8);
      pav[u] = *(const float4*)(A + (row0 + t0 + tok) * 64 + g * 4);
    }
  };
  loadG(0);

  for (int ks = 0; ks < 8; ++ks) {
    __syncthreads();
#pragma unroll
    for (int u = 0; u < 2; ++u) {
      int idx = tid + u * 256;
      int tok = idx & 31, g = idx >> 5;
#pragma unroll
      for (int i = 0; i < 8; ++i) KVt[g * 8 + i][tok] = (unsigned short)pkv[u][i];
      At[g * 4 + 0][tok] = f2bf(pav[u].x);
      At[g * 4 + 1][tok] = f2bf(pav[u].y);
      At[g * 4 + 2][tok] = f2bf(pav[u].z);
      At[g * 4 + 3][tok] = f2bf(pav[u].w);
    }
    __syncthreads();
    if (ks + 1 < 8) loadG((ks + 1) * 32);
    bf16x8 af[4], bfr[2];
#pragma unroll
    for (int r = 0; r < 4; ++r) af[r] = *(const bf16x8*)&At[r * 16 + m16][quad * 8];
#pragma unroll
    for (int c = 0; c < 2; ++c) bfr[c] = *(const bf16x8*)&KVt[w * 32 + c * 16 + m16][quad * 8];
#pragma unroll
    for (int r = 0; r < 4; ++r)
#pragma unroll
      for (int c = 0; c < 2; ++c)
        acc[r][c] = __builtin_amdgcn_mfma_f32_16x16x32_bf16(af[r], bfr[c], acc[r][c], 0, 0, 0);
  }

  float* pp = part + (((size_t)b * 64 + tch) * 64) * 512 + cb0;
#pragma unroll
  for (int r = 0; r < 4; ++r)
#pragma unroll
    for (int c = 0; c < 2; ++c)
#pragma unroll
      for (int i = 0; i < 4; ++i) {
        int cl = r * 16 + quad * 4 + i;
        int ch = w * 32 + c * 16 + m16;
        pp[(size_t)cl * 512 + ch] = acc[r][c][i];
      }
}

// reduce 64 chunks; fold 1/denom and qk scale. part[b][tch][cl][ch]
__global__ __launch_bounds__(256) void pool2(const float* __restrict__ part,
                                             const float* __restrict__ asum,
                                             float* __restrict__ kcvc) {
  int id = blockIdx.x * 256 + threadIdx.x;  // 0..131071
  int c = id & 511;
  int cl = (id >> 9) & 63;
  int b = id >> 15;
  const float* pp = part + ((size_t)b * 64 * 64 + cl) * 512 + c;
  float s = 0.f;
#pragma unroll 4
  for (int t = 0; t < 64; ++t) s += pp[(size_t)t * 32768];
  float denom = asum[b * 64 + cl] + 1e-8f;
  int p = c >> 8, h = (c >> 5) & 7, d = c & 31;
  float scale = p ? 1.0f : 0.17677669529663687f;  // 1/sqrt(32) on K part
  kcvc[((((size_t)b * 2 + p) * 8 + h) * 64 + cl) * 32 + d] = s * scale / denom;
}

__global__ __launch_bounds__(256) void asum_kernel(const float* __restrict__ A,
                                                   float* __restrict__ asum) {
  __shared__ float red[4][64];
  const int ch = blockIdx.x, b = blockIdx.y;
  const int jq = threadIdx.x >> 6, k = threadIdx.x & 63;
  const size_t row0 = (size_t)b * NTOK + (size_t)ch * 256;
  const float* ap = A + (row0 + jq) * 64 + k;
  float s = 0.f;
#pragma unroll 4
  for (int j = 0; j < 64; ++j) s += ap[(size_t)j * 256];
  red[jq][k] = s;
  __syncthreads();
  if (threadIdx.x < 64) {
    float v = red[0][k] + red[1][k] + red[2][k] + red[3][k];
    atomicAdd(&asum[b * 64 + k], v);
  }
}

__global__ __launch_bounds__(256) void bias_kernel(const float* __restrict__ A,
                                                   const float* __restrict__ cb,
                                                   float* __restrict__ bout) {
  size_t i = (size_t)blockIdx.x * 256 + threadIdx.x;
  const float* ar = A + i * 64;
  float a[64];
#pragma unroll
  for (int u = 0; u < 16; ++u) *(float4*)(a + 4 * u) = *(const float4*)(ar + 4 * u);
  float o[64];
#pragma unroll
  for (int l = 0; l < 64; ++l) o[l] = 0.f;
#pragma unroll
  for (int j = 0; j < 64; ++j)
#pragma unroll
    for (int l = 0; l < 64; ++l) o[l] = fmaf(a[j], cb[j * 64 + l], o[l]);
  float* op = bout + i * 64;
#pragma unroll
  for (int u = 0; u < 16; ++u) *(float4*)(op + 4 * u) = *(float4*)(o + 4 * u);
}

// one thread per (token, head); q bf16 in, x bf16 out (q slot of qkv)
__global__ __launch_bounds__(256) void attn_kernel(unsigned short* __restrict__ qkv,
                                                   const float* __restrict__ kcvc,
                                                   const float* __restrict__ bbuf) {
  const int n = blockIdx.x * 256 + threadIdx.x;
  const int h = blockIdx.y, b = blockIdx.z;
  const size_t rown = (size_t)b * NTOK + n;

  unsigned short* qp = qkv + rown * 768 + h * 32;
  float q[32];
#pragma unroll
  for (int u = 0; u < 4; ++u) {
    ushort8 qv = *(const ushort8*)(qp + 8 * u);
#pragma unroll
    for (int j = 0; j < 8; ++j) q[8 * u + j] = bf2f((unsigned short)qv[j]);
  }

  float sc[64];
#pragma unroll
  for (int u = 0; u < 16; ++u)
    *(float4*)(sc + 4 * u) = *(const float4*)(bbuf + rown * 64 + 4 * u);

  const float* kc = kcvc + (((size_t)b * 2 + 0) * 8 + h) * 2048;
  const float* vc = kcvc + (((size_t)b * 2 + 1) * 8 + h) * 2048;

#pragma unroll
  for (int k = 0; k < 64; ++k) {
    float s = sc[k];
#pragma unroll
    for (int d = 0; d < 32; ++d) s = fmaf(q[d], kc[k * 32 + d], s);
    sc[k] = s;
  }

  float m = sc[0];
#pragma unroll
  for (int k = 1; k < 64; ++k) m = fmaxf(m, sc[k]);
  float l = 0.f;
#pragma unroll
  for (int k = 0; k < 64; ++k) {
    float e = __expf(sc[k] - m);
    sc[k] = e;
    l += e;
  }
  float rl = 1.f / l;

  float xo[32];
#pragma unroll
  for (int d = 0; d < 32; ++d) xo[d] = 0.f;
#pragma unroll
  for (int k = 0; k < 64; ++k) {
    float p = sc[k];
#pragma unroll
    for (int d = 0; d < 32; ++d) xo[d] = fmaf(p, vc[k * 32 + d], xo[d]);
  }

  unsigned short xh[32];
#pragma unroll
  for (int d = 0; d < 32; ++d) xh[d] = f2bf(xo[d] * rl);
#pragma unroll
  for (int i = 0; i < 4; ++i) *(ushort8*)(qp + 8 * i) = *(ushort8*)&xh[8 * i];
}

extern "C" void kernel_launch(void* const* d_in, const int* in_sizes, int n_in,
                              void* d_out, int out_size, void* d_ws, size_t ws_size,
                              hipStream_t stream) {
  const float* voxel  = (const float*)d_in[0];
  const float* A      = (const float*)d_in[1];
  const float* w_qkv  = (const float*)d_in[2];
  const float* w_proj = (const float*)d_in[3];
  const float* b_proj = (const float*)d_in[4];
  const float* cb     = (const float*)d_in[5];
  float* out = (float*)d_out;
  (void)in_sizes; (void)n_in; (void)out_size; (void)ws_size;

  // layout (bytes): qkv bf16 100663296 | part fp32 33554432 (alias bbuf 16.8MB)
  //                 | kcvc 524288 | asum 1024 | wqT 393216 | wpT 131072  ~= 135 MB
  char* wsb = (char*)d_ws;
  unsigned short* qkv = (unsigned short*)wsb;
  float* part = (float*)(wsb + 100663296);
  float* bbuf = part;  // aliased: part dead (after pool2) before bias writes
  float* kcvc = part + 8388608;
  float* asum = kcvc + 131072;
  unsigned short* wqT = (unsigned short*)(asum + 256);
  unsigned short* wpT = wqT + 196608;

  zero_f<<<1, 256, 0, stream>>>(asum, 256);
  convw<<<1024, 256, 0, stream>>>(w_qkv, w_proj, wqT, wpT);

  // qkv(bf16) = voxel @ w_qkv
  gemm_mfma<1, 0, 1><<<dim3(6, 512), 256, 0, stream>>>(voxel, wqT, nullptr, qkv,
                                                       768, 256, 256);

  asum_kernel<<<dim3(64, BATCH), 256, 0, stream>>>(A, asum);
  pool_mfma<<<dim3(64, 4, BATCH), 256, 0, stream>>>(A, qkv, part);
  pool2<<<512, 256, 0, stream>>>(part, asum, kcvc);

  bias_kernel<<<(BATCH * NTOK) / 256, 256, 0, stream>>>(A, cb, bbuf);

  attn_kernel<<<dim3(NTOK / 256, 8, BATCH), 256, 0, stream>>>(qkv, kcvc, bbuf);

  // out = x @ w_proj + b_proj : x bf16 in q slot of qkv (lda 768 shorts)
  gemm_mfma<0, 1, 0><<<dim3(2, 512), 256, 0, stream>>>(qkv, wpT, b_proj, out,
                                                       256, 256, 768);
}

// Round 6
// 319.278 us; speedup vs baseline: 4.3000x; 1.3473x over previous
//
#include <hip/hip_runtime.h>

#define NTOK 16384
#define BATCH 4

typedef __attribute__((ext_vector_type(8))) short bf16x8;
typedef __attribute__((ext_vector_type(8))) unsigned short ushort8;
typedef __attribute__((ext_vector_type(4))) float f32x4;

__device__ __forceinline__ unsigned short f2bf(float f) {
  union { float f; unsigned int u; } c; c.f = f;
  unsigned int r = c.u + 0x7fff + ((c.u >> 16) & 1);  // RTN-even
  return (unsigned short)(r >> 16);
}

__global__ __launch_bounds__(256) void zero_f(float* __restrict__ p, int n) {
  int i = blockIdx.x * 256 + threadIdx.x;
  if (i < n) p[i] = 0.f;
}

// transpose+convert weights; block 1024 converts cb -> cbbT[l][j] = cb[j][l]
__global__ __launch_bounds__(256) void convw(const float* __restrict__ w_qkv,
                                             const float* __restrict__ w_proj,
                                             const float* __restrict__ cb,
                                             unsigned short* __restrict__ wqT,
                                             unsigned short* __restrict__ wpT,
                                             unsigned short* __restrict__ cbbT) {
  int n = blockIdx.x, k = threadIdx.x;
  if (n < 768) wqT[n * 256 + k] = f2bf(w_qkv[(size_t)k * 768 + n]);
  else if (n < 1024) wpT[(n - 768) * 256 + k] = f2bf(w_proj[(size_t)k * 256 + (n - 768)]);
  else if (k < 64) {
    for (int j = 0; j < 64; ++j) cbbT[k * 64 + j] = f2bf(cb[j * 64 + k]);
  }
}

// C[M,N] = A[M,K] @ BT[N,K]^T (+bias). MFMA bf16. Tile 128x128, BK=64, 4 waves.
// XCD-swizzled block mapping: same-A-row tiles land on one XCD's L2.
template <int A_FP32, int ADD_BIAS, int C_BF16>
__global__ __launch_bounds__(256) void gemm_mfma(const void* __restrict__ Av,
                                                 const unsigned short* __restrict__ BT,
                                                 const float* __restrict__ bias,
                                                 void* __restrict__ Cv,
                                                 int N, int K, int lda) {
  __shared__ unsigned short As[128][72];
  __shared__ unsigned short Bs[128][72];
  const int tid = threadIdx.x;
  // XCD swizzle: dispatch id c mod 8 = XCD (heuristic; correctness-neutral)
  int flat = blockIdx.y * gridDim.x + blockIdx.x;
  int xc = flat & 7, t = flat >> 3;
  int gx = gridDim.x, ypx = gridDim.y >> 3;
  int bx = t % gx, by = xc * ypx + t / gx;
  const int bn = bx * 128, bm = by * 128;
  const int lane = tid & 63;
  const int wv = tid >> 6;
  const int wm = wv & 1, wn = wv >> 1;
  const int m16 = lane & 15, quad = lane >> 4;

  const float* Af = (const float*)Av;
  const unsigned short* Ab = (const unsigned short*)Av;

  const int srow = tid >> 1;
  const int scol = (tid & 1) * 32;

  f32x4 acc[4][4];
#pragma unroll
  for (int r = 0; r < 4; ++r)
#pragma unroll
    for (int c = 0; c < 4; ++c) acc[r][c] = (f32x4){0.f, 0.f, 0.f, 0.f};

  float4 pa[8];
  ushort8 pab[4], pb[4];

  auto loadA = [&](int k0) {
    if (A_FP32) {
      const float* g = Af + (size_t)(bm + srow) * lda + k0 + scol;
#pragma unroll
      for (int i = 0; i < 8; ++i) pa[i] = *(const float4*)(g + 4 * i);
    } else {
      const unsigned short* g = Ab + (size_t)(bm + srow) * lda + k0 + scol;
#pragma unroll
      for (int i = 0; i < 4; ++i) pab[i] = *(const ushort8*)(g + 8 * i);
    }
  };
  auto loadB = [&](int k0) {
    const unsigned short* g = BT + (size_t)(bn + srow) * K + k0 + scol;
#pragma unroll
    for (int i = 0; i < 4; ++i) pb[i] = *(const ushort8*)(g + 8 * i);
  };

  loadA(0);
  loadB(0);

  const int nkt = K >> 6;
  for (int kt = 0; kt < nkt; ++kt) {
    __syncthreads();
    if (A_FP32) {
      unsigned short h[32];
#pragma unroll
      for (int i = 0; i < 8; ++i) {
        h[4 * i + 0] = f2bf(pa[i].x);
        h[4 * i + 1] = f2bf(pa[i].y);
        h[4 * i + 2] = f2bf(pa[i].z);
        h[4 * i + 3] = f2bf(pa[i].w);
      }
#pragma unroll
      for (int i = 0; i < 4; ++i) *(ushort8*)&As[srow][scol + 8 * i] = *(ushort8*)&h[8 * i];
    } else {
#pragma unroll
      for (int i = 0; i < 4; ++i) *(ushort8*)&As[srow][scol + 8 * i] = pab[i];
    }
#pragma unroll
    for (int i = 0; i < 4; ++i) *(ushort8*)&Bs[srow][scol + 8 * i] = pb[i];
    __syncthreads();
    if (kt + 1 < nkt) {
      loadA((kt + 1) << 6);
      loadB((kt + 1) << 6);
    }
#pragma unroll
    for (int ks = 0; ks < 64; ks += 32) {
      bf16x8 af[4], bf[4];
#pragma unroll
      for (int r = 0; r < 4; ++r)
        af[r] = *(const bf16x8*)&As[wm * 64 + r * 16 + m16][ks + quad * 8];
#pragma unroll
      for (int c = 0; c < 4; ++c)
        bf[c] = *(const bf16x8*)&Bs[wn * 64 + c * 16 + m16][ks + quad * 8];
#pragma unroll
      for (int r = 0; r < 4; ++r)
#pragma unroll
        for (int c = 0; c < 4; ++c)
          acc[r][c] = __builtin_amdgcn_mfma_f32_16x16x32_bf16(af[r], bf[c], acc[r][c], 0, 0, 0);
    }
  }

#pragma unroll
  for (int c = 0; c < 4; ++c) {
    int col = bn + wn * 64 + c * 16 + m16;
    float bv = ADD_BIAS ? bias[col] : 0.f;
#pragma unroll
    for (int r = 0; r < 4; ++r) {
      int row0 = bm + wm * 64 + r * 16 + quad * 4;
#pragma unroll
      for (int i = 0; i < 4; ++i) {
        if (C_BF16)
          ((unsigned short*)Cv)[(size_t)(row0 + i) * N + col] = f2bf(acc[r][c][i] + bv);
        else
          ((float*)Cv)[(size_t)(row0 + i) * N + col] = acc[r][c][i] + bv;
      }
    }
  }
}

// ---- pooling via MFMA: part[b][tch][cl 64][ch 512] over 256-token chunks ----
__global__ __launch_bounds__(256) void pool_mfma(const float* __restrict__ A,
                                                 const unsigned short* __restrict__ qkv,
                                                 float* __restrict__ part) {
  __shared__ unsigned short At[64][40];
  __shared__ unsigned short KVt[128][40];
  const int tid = threadIdx.x;
  const int tch = blockIdx.x, cblk = blockIdx.y, b = blockIdx.z;
  const int w = tid >> 6, lane = tid & 63;
  const int m16 = lane & 15, quad = lane >> 4;
  const size_t row0 = (size_t)b * NTOK + (size_t)tch * 256;
  const int cb0 = cblk * 128;

  f32x4 acc[4][2];
#pragma unroll
  for (int r = 0; r < 4; ++r)
#pragma unroll
    for (int c = 0; c < 2; ++c) acc[r][c] = (f32x4){0.f, 0.f, 0.f, 0.f};

  ushort8 pkv[2];
  float4 pav[2];
  auto loadG = [&](int t0) {
#pragma unroll
    for (int u = 0; u < 2; ++u) {
      int idx = tid + u * 256;
      int tok = idx & 31, g = idx >> 5;
      pkv[u] = *(const ushort8*)(qkv + (row0 + t0 + tok) * 768 + 256 + cb0 + g * 8);
      pav[u] = *(const float4*)(A + (row0 + t0 + tok) * 64 + g * 4);
    }
  };
  loadG(0);

  for (int ks = 0; ks < 8; ++ks) {
    __syncthreads();
#pragma unroll
    for (int u = 0; u < 2; ++u) {
      int idx = tid + u * 256;
      int tok = idx & 31, g = idx >> 5;
#pragma unroll
      for (int i = 0; i < 8; ++i) KVt[g * 8 + i][tok] = (unsigned short)pkv[u][i];
      At[g * 4 + 0][tok] = f2bf(pav[u].x);
      At[g * 4 + 1][tok] = f2bf(pav[u].y);
      At[g * 4 + 2][tok] = f2bf(pav[u].z);
      At[g * 4 + 3][tok] = f2bf(pav[u].w);
    }
    __syncthreads();
    if (ks + 1 < 8) loadG((ks + 1) * 32);
    bf16x8 af[4], bfr[2];
#pragma unroll
    for (int r = 0; r < 4; ++r) af[r] = *(const bf16x8*)&At[r * 16 + m16][quad * 8];
#pragma unroll
    for (int c = 0; c < 2; ++c) bfr[c] = *(const bf16x8*)&KVt[w * 32 + c * 16 + m16][quad * 8];
#pragma unroll
    for (int r = 0; r < 4; ++r)
#pragma unroll
      for (int c = 0; c < 2; ++c)
        acc[r][c] = __builtin_amdgcn_mfma_f32_16x16x32_bf16(af[r], bfr[c], acc[r][c], 0, 0, 0);
  }

  float* pp = part + (((size_t)b * 64 + tch) * 64) * 512 + cb0;
#pragma unroll
  for (int r = 0; r < 4; ++r)
#pragma unroll
    for (int c = 0; c < 2; ++c)
#pragma unroll
      for (int i = 0; i < 4; ++i) {
        int cl = r * 16 + quad * 4 + i;
        int ch = w * 32 + c * 16 + m16;
        pp[(size_t)cl * 512 + ch] = acc[r][c][i];
      }
}

// reduce 64 chunks -> bf16 kcb[b][h][cl][d] (scaled) and vcbT[b][h][d][cl]
__global__ __launch_bounds__(256) void pool2(const float* __restrict__ part,
                                             const float* __restrict__ asum,
                                             unsigned short* __restrict__ kcb,
                                             unsigned short* __restrict__ vcbT) {
  int id = blockIdx.x * 256 + threadIdx.x;  // 0..131071
  int c = id & 511;
  int cl = (id >> 9) & 63;
  int b = id >> 15;
  const float* pp = part + ((size_t)b * 64 * 64 + cl) * 512 + c;
  float s = 0.f;
#pragma unroll 4
  for (int t = 0; t < 64; ++t) s += pp[(size_t)t * 32768];
  float denom = asum[b * 64 + cl] + 1e-8f;
  int p = c >> 8, h = (c >> 5) & 7, d = c & 31;
  if (p == 0)
    kcb[(((size_t)b * 8 + h) * 64 + cl) * 32 + d] = f2bf(s * 0.17677669529663687f / denom);
  else
    vcbT[(((size_t)b * 8 + h) * 32 + d) * 64 + cl] = f2bf(s / denom);
}

__global__ __launch_bounds__(256) void asum_kernel(const float* __restrict__ A,
                                                   float* __restrict__ asum) {
  __shared__ float red[4][64];
  const int ch = blockIdx.x, b = blockIdx.y;
  const int jq = threadIdx.x >> 6, k = threadIdx.x & 63;
  const size_t row0 = (size_t)b * NTOK + (size_t)ch * 256;
  const float* ap = A + (row0 + jq) * 64 + k;
  float s = 0.f;
#pragma unroll 4
  for (int j = 0; j < 64; ++j) s += ap[(size_t)j * 256];
  red[jq][k] = s;
  __syncthreads();
  if (threadIdx.x < 64) {
    float v = red[0][k] + red[1][k] + red[2][k] + red[3][k];
    atomicAdd(&asum[b * 64 + k], v);
  }
}

// ---- fused attention: scores = [q|A]@[kc;cbT]^T (MFMA, bias folded as K-dims),
// LDS softmax, x = P@vcT (MFMA). 128 tokens x 1 head per block. ----
__global__ __launch_bounds__(256) void attn_mfma(const float* __restrict__ A,
                                                 unsigned short* __restrict__ qkv,
                                                 const unsigned short* __restrict__ kcb,
                                                 const unsigned short* __restrict__ vcbT,
                                                 const unsigned short* __restrict__ cbbT) {
  __shared__ __align__(16) char lds[62976];
  unsigned short* QA = (unsigned short*)lds;             // [128][104]
  unsigned short* SB = (unsigned short*)(lds + 26624);   // [64][104]
  float* S = (float*)lds;                                // [128][68] (alias QA+SB)
  unsigned short* P = (unsigned short*)(lds + 39936);    // [128][72]
  unsigned short* VT = (unsigned short*)(lds + 58368);   // [32][72]

  const int tid = threadIdx.x;
  const int nb = blockIdx.x, h = blockIdx.y, b = blockIdx.z;
  const int w = tid >> 6, lane = tid & 63;
  const int m16 = lane & 15, quad = lane >> 4;
  const size_t row0 = (size_t)b * NTOK + (size_t)nb * 128;

  // ---- stage ----
  {
    int r = tid >> 1, half = tid & 1;
    const unsigned short* qp = qkv + (row0 + r) * 768 + h * 32 + half * 16;
    ushort8 q0 = *(const ushort8*)qp;
    ushort8 q1 = *(const ushort8*)(qp + 8);
    *(ushort8*)&QA[r * 104 + half * 16] = q0;
    *(ushort8*)&QA[r * 104 + half * 16 + 8] = q1;

    const float* ap = A + (row0 + r) * 64 + half * 32;
    unsigned short hb[32];
#pragma unroll
    for (int u = 0; u < 8; ++u) {
      float4 v = *(const float4*)(ap + 4 * u);
      hb[4 * u + 0] = f2bf(v.x); hb[4 * u + 1] = f2bf(v.y);
      hb[4 * u + 2] = f2bf(v.z); hb[4 * u + 3] = f2bf(v.w);
    }
#pragma unroll
    for (int u = 0; u < 4; ++u)
      *(ushort8*)&QA[r * 104 + 32 + half * 32 + 8 * u] = *(ushort8*)&hb[8 * u];

    if (tid < 64) {
      const unsigned short* kp = kcb + (((size_t)b * 8 + h) * 64 + tid) * 32;
#pragma unroll
      for (int u = 0; u < 4; ++u)
        *(ushort8*)&SB[tid * 104 + 8 * u] = *(const ushort8*)(kp + 8 * u);
    }
    if (tid < 128) {
      int l = tid >> 1, off = (tid & 1) * 32;
      const unsigned short* cp = cbbT + l * 64 + off;
#pragma unroll
      for (int u = 0; u < 4; ++u)
        *(ushort8*)&SB[l * 104 + 32 + off + 8 * u] = *(const ushort8*)(cp + 8 * u);
    }
    if (tid < 64) {
      int d = tid >> 1, off = (tid & 1) * 32;
      const unsigned short* vp = vcbT + (((size_t)b * 8 + h) * 32 + d) * 64 + off;
#pragma unroll
      for (int u = 0; u < 4; ++u)
        *(ushort8*)&VT[d * 72 + off + 8 * u] = *(const ushort8*)(vp + 8 * u);
    }
  }
  __syncthreads();

  // ---- scores ----
  f32x4 acc[2][4];
#pragma unroll
  for (int r = 0; r < 2; ++r)
#pragma unroll
    for (int c = 0; c < 4; ++c) acc[r][c] = (f32x4){0.f, 0.f, 0.f, 0.f};
#pragma unroll
  for (int kc3 = 0; kc3 < 96; kc3 += 32) {
    bf16x8 af[2], bf[4];
#pragma unroll
    for (int rt = 0; rt < 2; ++rt)
      af[rt] = *(const bf16x8*)&QA[(w * 32 + rt * 16 + m16) * 104 + kc3 + quad * 8];
#pragma unroll
    for (int nt = 0; nt < 4; ++nt)
      bf[nt] = *(const bf16x8*)&SB[(nt * 16 + m16) * 104 + kc3 + quad * 8];
#pragma unroll
    for (int rt = 0; rt < 2; ++rt)
#pragma unroll
      for (int nt = 0; nt < 4; ++nt)
        acc[rt][nt] = __builtin_amdgcn_mfma_f32_16x16x32_bf16(af[rt], bf[nt], acc[rt][nt], 0, 0, 0);
  }
  __syncthreads();  // frag reads done before S overwrites QA/SB

#pragma unroll
  for (int rt = 0; rt < 2; ++rt)
#pragma unroll
    for (int nt = 0; nt < 4; ++nt)
#pragma unroll
      for (int i = 0; i < 4; ++i)
        S[(w * 32 + rt * 16 + quad * 4 + i) * 68 + nt * 16 + m16] = acc[rt][nt][i];
  __syncthreads();

  // ---- softmax (one thread per token row) ----
  if (tid < 128) {
    float sc[64];
#pragma unroll
    for (int u = 0; u < 16; ++u) *(float4*)(sc + 4 * u) = *(const float4*)&S[tid * 68 + 4 * u];
    float m = sc[0];
#pragma unroll
    for (int k = 1; k < 64; ++k) m = fmaxf(m, sc[k]);
    float l = 0.f;
#pragma unroll
    for (int k = 0; k < 64; ++k) {
      float e = __expf(sc[k] - m);
      sc[k] = e;
      l += e;
    }
    float rl = 1.f / l;
    unsigned short hp[64];
#pragma unroll
    for (int k = 0; k < 64; ++k) hp[k] = f2bf(sc[k] * rl);
#pragma unroll
    for (int u = 0; u < 8; ++u) *(ushort8*)&P[tid * 72 + 8 * u] = *(ushort8*)&hp[8 * u];
  }
  __syncthreads();

  // ---- x = P @ vcT ----
  f32x4 acc2[2][2];
#pragma unroll
  for (int r = 0; r < 2; ++r)
#pragma unroll
    for (int c = 0; c < 2; ++c) acc2[r][c] = (f32x4){0.f, 0.f, 0.f, 0.f};
#pragma unroll
  for (int kch = 0; kch < 64; kch += 32) {
    bf16x8 af2[2], bf2[2];
#pragma unroll
    for (int rt = 0; rt < 2; ++rt)
      af2[rt] = *(const bf16x8*)&P[(w * 32 + rt * 16 + m16) * 72 + kch + quad * 8];
#pragma unroll
    for (int nt = 0; nt < 2; ++nt)
      bf2[nt] = *(const bf16x8*)&VT[(nt * 16 + m16) * 72 + kch + quad * 8];
#pragma unroll
    for (int rt = 0; rt < 2; ++rt)
#pragma unroll
      for (int nt = 0; nt < 2; ++nt)
        acc2[rt][nt] = __builtin_amdgcn_mfma_f32_16x16x32_bf16(af2[rt], bf2[nt], acc2[rt][nt], 0, 0, 0);
  }

#pragma unroll
  for (int rt = 0; rt < 2; ++rt)
#pragma unroll
    for (int nt = 0; nt < 2; ++nt)
#pragma unroll
      for (int i = 0; i < 4; ++i) {
        int tr = w * 32 + rt * 16 + quad * 4 + i;
        int d = nt * 16 + m16;
        qkv[(row0 + tr) * 768 + h * 32 + d] = f2bf(acc2[rt][nt][i]);
      }
}

extern "C" void kernel_launch(void* const* d_in, const int* in_sizes, int n_in,
                              void* d_out, int out_size, void* d_ws, size_t ws_size,
                              hipStream_t stream) {
  const float* voxel  = (const float*)d_in[0];
  const float* A      = (const float*)d_in[1];
  const float* w_qkv  = (const float*)d_in[2];
  const float* w_proj = (const float*)d_in[3];
  const float* b_proj = (const float*)d_in[4];
  const float* cb     = (const float*)d_in[5];
  float* out = (float*)d_out;
  (void)in_sizes; (void)n_in; (void)out_size; (void)ws_size;

  // bytes: qkv bf16 100663296 | part 33554432 | asum 1024 | wqT 393216 |
  //        wpT 131072 | kcb 131072 | vcbT 131072 | cbbT 8192   ~= 135 MB
  char* wsb = (char*)d_ws;
  unsigned short* qkv = (unsigned short*)wsb;
  float* part = (float*)(wsb + 100663296);
  float* asum = (float*)(wsb + 100663296 + 33554432);
  unsigned short* wqT  = (unsigned short*)(wsb + 134218752);
  unsigned short* wpT  = wqT + 196608;
  unsigned short* kcb  = wpT + 65536;
  unsigned short* vcbT = kcb + 65536;
  unsigned short* cbbT = vcbT + 65536;

  zero_f<<<1, 256, 0, stream>>>(asum, 256);
  convw<<<1025, 256, 0, stream>>>(w_qkv, w_proj, cb, wqT, wpT, cbbT);

  // qkv(bf16) = voxel @ w_qkv
  gemm_mfma<1, 0, 1><<<dim3(6, 512), 256, 0, stream>>>(voxel, wqT, nullptr, qkv,
                                                       768, 256, 256);

  asum_kernel<<<dim3(64, BATCH), 256, 0, stream>>>(A, asum);
  pool_mfma<<<dim3(64, 4, BATCH), 256, 0, stream>>>(A, qkv, part);
  pool2<<<512, 256, 0, stream>>>(part, asum, kcb, vcbT);

  // fused attention (bias folded in); x bf16 -> q slot of qkv
  attn_mfma<<<dim3(NTOK / 128, 8, BATCH), 256, 0, stream>>>(A, qkv, kcb, vcbT, cbbT);

  // out = x @ w_proj + b_proj : x bf16 in q slot of qkv (lda 768 shorts)
  gemm_mfma<0, 1, 0><<<dim3(2, 512), 256, 0, stream>>>(qkv, wpT, b_proj, out,
                                                       256, 256, 768);
}